// Round 1
// baseline (223.269 us; speedup 1.0000x reference)
//
#include <hip/hip_runtime.h>
#include <math.h>

#define NE 8
#define TPW 4           // tokens per wave
#define TOKENS_PER_BLOCK 16
#define EPS_F32 1.1920929e-07f

__device__ __forceinline__ void fma8(float xs, const float4& lo, const float4& hi, float* a) {
    a[0] = fmaf(xs, lo.x, a[0]);
    a[1] = fmaf(xs, lo.y, a[1]);
    a[2] = fmaf(xs, lo.z, a[2]);
    a[3] = fmaf(xs, lo.w, a[3]);
    a[4] = fmaf(xs, hi.x, a[4]);
    a[5] = fmaf(xs, hi.y, a[5]);
    a[6] = fmaf(xs, hi.z, a[6]);
    a[7] = fmaf(xs, hi.w, a[7]);
}

__global__ __launch_bounds__(256, 2)
void topk_gate(const float* __restrict__ x,
               const float* __restrict__ prompt,
               const float* __restrict__ W,
               const float* __restrict__ b,
               float* __restrict__ out,
               int tokens)
{
    const int lane = threadIdx.x & 63;
    const int wave = threadIdx.x >> 6;
    const int tbase = blockIdx.x * TOKENS_PER_BLOCK + wave * TPW;

    float acc[TPW][NE];
#pragma unroll
    for (int t = 0; t < TPW; ++t)
#pragma unroll
        for (int e = 0; e < NE; ++e) acc[t][e] = 0.f;

    // ---- main loop over model_dim: 4096 / (64 lanes * 4 floats) = 16 iters ----
#pragma unroll 2
    for (int i = 0; i < 16; ++i) {
        const int k = i * 256 + lane * 4;
        float4 wlo[4], whi[4];
#pragma unroll
        for (int j = 0; j < 4; ++j) {
            wlo[j] = *(const float4*)(W + (size_t)(k + j) * 8);
            whi[j] = *(const float4*)(W + (size_t)(k + j) * 8 + 4);
        }
#pragma unroll
        for (int t = 0; t < TPW; ++t) {
            const float4 xv = *(const float4*)(x + (size_t)(tbase + t) * 4096 + k);
            fma8(xv.x, wlo[0], whi[0], acc[t]);
            fma8(xv.y, wlo[1], whi[1], acc[t]);
            fma8(xv.z, wlo[2], whi[2], acc[t]);
            fma8(xv.w, wlo[3], whi[3], acc[t]);
        }
    }

    // ---- prompt part: 64 dims, lanes 0..15 take 4 each ----
    if (lane < 16) {
        const int k = lane * 4;
        float4 wlo[4], whi[4];
#pragma unroll
        for (int j = 0; j < 4; ++j) {
            wlo[j] = *(const float4*)(W + (size_t)(4096 + k + j) * 8);
            whi[j] = *(const float4*)(W + (size_t)(4096 + k + j) * 8 + 4);
        }
#pragma unroll
        for (int t = 0; t < TPW; ++t) {
            const float4 pv = *(const float4*)(prompt + (size_t)(tbase + t) * 64 + k);
            fma8(pv.x, wlo[0], whi[0], acc[t]);
            fma8(pv.y, wlo[1], whi[1], acc[t]);
            fma8(pv.z, wlo[2], whi[2], acc[t]);
            fma8(pv.w, wlo[3], whi[3], acc[t]);
        }
    }

    // ---- butterfly reduce: every lane ends with full logits for all 4 tokens ----
#pragma unroll
    for (int t = 0; t < TPW; ++t)
#pragma unroll
        for (int e = 0; e < NE; ++e) {
            float v = acc[t][e];
#pragma unroll
            for (int off = 32; off >= 1; off >>= 1)
                v += __shfl_xor(v, off, 64);
            acc[t][e] = v;
        }

    // ---- epilogue: lane = tt*16 + kk*8 + ee -> one mask element per lane ----
    const int tt = lane >> 4;
    const int kk = (lane >> 3) & 1;
    const int ee = lane & 7;

    float lg[NE];
#pragma unroll
    for (int e = 0; e < NE; ++e) {
        float v = acc[0][e];
        if (tt == 1) v = acc[1][e];
        if (tt == 2) v = acc[2][e];
        if (tt == 3) v = acc[3][e];
        lg[e] = v + b[e];
    }

    // top-2, strict > so smallest index wins ties (jax.lax.top_k semantics)
    float v0 = lg[0]; int i0 = 0;
#pragma unroll
    for (int e = 1; e < NE; ++e)
        if (lg[e] > v0) { v0 = lg[e]; i0 = e; }
    float v1 = (i0 == 0) ? lg[1] : lg[0];
    int   i1 = (i0 == 0) ? 1 : 0;
#pragma unroll
    for (int e = 0; e < NE; ++e) {
        if (e != i0 && lg[e] > v1) { v1 = lg[e]; i1 = e; }
    }

    // softmax over 8 logits (max = v0)
    float s = 0.f;
#pragma unroll
    for (int e = 0; e < NE; ++e) s += __expf(lg[e] - v0);
    const float g0 = 1.0f / s;               // expf(v0 - v0) / s
    const float g1 = __expf(v1 - v0) / s;
    const float denom = fmaxf(g0 + g1, EPS_F32);

    // masks: out[t*16 + k*8 + e]; address = tbase*16 + lane -> fully coalesced
    const int sel = kk ? i1 : i0;
    const int t_global = tbase + tt;
    out[(size_t)t_global * 16 + kk * 8 + ee] = (ee == sel) ? 1.0f : 0.0f;

    // gates: out[tokens*16 + t*2 + k], written by lanes with (lane&15) < 2
    if ((lane & 15) < 2) {
        const float g = (ee == 0) ? (g0 / denom) : (g1 / denom);
        out[(size_t)tokens * 16 + (size_t)t_global * 2 + ee] = g;
    }
}

extern "C" void kernel_launch(void* const* d_in, const int* in_sizes, int n_in,
                              void* d_out, int out_size, void* d_ws, size_t ws_size,
                              hipStream_t stream) {
    const float* x      = (const float*)d_in[0];
    const float* prompt = (const float*)d_in[1];
    const float* W      = (const float*)d_in[2];
    const float* b      = (const float*)d_in[3];
    float* out          = (float*)d_out;

    const int tokens = in_sizes[0] / 4096;           // 8192
    const int grid   = tokens / TOKENS_PER_BLOCK;    // 512

    hipLaunchKernelGGL(topk_gate, dim3(grid), dim3(256), 0, stream,
                       x, prompt, W, b, out, tokens);
}